// Round 2
// baseline (297.867 us; speedup 1.0000x reference)
//
#include <hip/hip_runtime.h>
#include <hip/hip_bf16.h>

// Problem constants (fixed by setup_inputs)
constexpr int kH  = 112;
constexpr int kW  = 112;
constexpr int kC  = 64;
constexpr int kB  = 2;
constexpr int kHW = kH * kW;          // 12544
constexpr int kNP = kB * kHW;         // 25088 pixels

constexpr float kLog2e = 1.4426950408889634f;

// ---------------------------------------------------------------------------
// Kernel 1: g = w1 @ f_guide + b1 ; s = w2 @ f_source + b2  (per-pixel 1x1)
// 8 lanes per pixel, 8 channels per lane. Output pixel-major (B,H,W,64) fp32.
// ---------------------------------------------------------------------------
__global__ __launch_bounds__(256)
void conv_gs(const float* __restrict__ fg, const float* __restrict__ fs,
             const float* __restrict__ w1, const float* __restrict__ b1,
             const float* __restrict__ w2, const float* __restrict__ b2,
             float* __restrict__ gw, float* __restrict__ sw, int nGroups)
{
    __shared__ float wt1[64 * 64];   // wt1[c][o] = w1[o][c]
    __shared__ float wt2[64 * 64];
    for (int idx = threadIdx.x; idx < 4096; idx += 256) {
        const int o = idx >> 6, c = idx & 63;
        wt1[c * 64 + o] = w1[idx];
        wt2[c * 64 + o] = w2[idx];
    }
    __syncthreads();

    const int tid = blockIdx.x * 256 + threadIdx.x;
    const int grp = tid >> 3;        // 8-lane group id = pixel id
    const int j   = tid & 7;         // lane owns channels 8j..8j+7

    float bb1[8], bb2[8];
    *(float4*)(bb1)     = *(const float4*)(b1 + 8 * j);
    *(float4*)(bb1 + 4) = *(const float4*)(b1 + 8 * j + 4);
    *(float4*)(bb2)     = *(const float4*)(b2 + 8 * j);
    *(float4*)(bb2 + 4) = *(const float4*)(b2 + 8 * j + 4);

    for (int p = grp; p < kNP; p += nGroups) {
        const int b   = p / kHW;
        const int rem = p - b * kHW;
        const int h   = rem / kW;
        const int w   = rem - h * kW;

        float xg[8], xs[8];
#pragma unroll
        for (int cc = 0; cc < 8; ++cc) {
            const int a = ((b * kC + 8 * j + cc) * kH + h) * kW + w;
            xg[cc] = fg[a];
            xs[cc] = fs[a];
        }

        float ag[8], as_[8];
#pragma unroll
        for (int k = 0; k < 8; ++k) { ag[k] = bb1[k]; as_[k] = bb2[k]; }

        for (int c0 = 0; c0 < 64; c0 += 8) {
            const int sl = c0 >> 3;
#pragma unroll
            for (int k = 0; k < 8; ++k) {
                const float xgc = __shfl(xg[k], sl, 8);
                const float xsc = __shfl(xs[k], sl, 8);
                const float* wr1 = &wt1[(c0 + k) * 64 + 8 * j];
                const float* wr2 = &wt2[(c0 + k) * 64 + 8 * j];
                const float4 a0 = *(const float4*)(wr1);
                const float4 a1 = *(const float4*)(wr1 + 4);
                const float4 c0v = *(const float4*)(wr2);
                const float4 c1v = *(const float4*)(wr2 + 4);
                ag[0] = fmaf(a0.x, xgc, ag[0]);  ag[1] = fmaf(a0.y, xgc, ag[1]);
                ag[2] = fmaf(a0.z, xgc, ag[2]);  ag[3] = fmaf(a0.w, xgc, ag[3]);
                ag[4] = fmaf(a1.x, xgc, ag[4]);  ag[5] = fmaf(a1.y, xgc, ag[5]);
                ag[6] = fmaf(a1.z, xgc, ag[6]);  ag[7] = fmaf(a1.w, xgc, ag[7]);
                as_[0] = fmaf(c0v.x, xsc, as_[0]); as_[1] = fmaf(c0v.y, xsc, as_[1]);
                as_[2] = fmaf(c0v.z, xsc, as_[2]); as_[3] = fmaf(c0v.w, xsc, as_[3]);
                as_[4] = fmaf(c1v.x, xsc, as_[4]); as_[5] = fmaf(c1v.y, xsc, as_[5]);
                as_[6] = fmaf(c1v.z, xsc, as_[6]); as_[7] = fmaf(c1v.w, xsc, as_[7]);
            }
        }
        float* gp = gw + (size_t)p * 64 + 8 * j;
        float* sp = sw + (size_t)p * 64 + 8 * j;
        *(float4*)(gp)     = make_float4(ag[0], ag[1], ag[2], ag[3]);
        *(float4*)(gp + 4) = make_float4(ag[4], ag[5], ag[6], ag[7]);
        *(float4*)(sp)     = make_float4(as_[0], as_[1], as_[2], as_[3]);
        *(float4*)(sp + 4) = make_float4(as_[4], as_[5], as_[6], as_[7]);
    }
}

// ---------------------------------------------------------------------------
// Attention phase helper: R = radius (5 -> 11x11, 2 -> 5x5).
// qs = query channels (this lane's 8) pre-scaled by log2(e).
// No-max softmax: scores bounded (|score| < ~50), exp2 cannot overflow fp32.
// OOB neighbors are zero vectors -> score 0 -> weight exp(0)=1 in the
// denominator, exactly matching the reference's zero-padded unfold.
// ---------------------------------------------------------------------------
template <int R, bool GUARD>
__device__ __forceinline__ void attn_phase(const float* __restrict__ base,
                                           const float qs[8], int h, int w, int j,
                                           float acc[8], float& l)
{
    for (int dy = -R; dy <= R; ++dy) {
        const int hh = h + dy;
        const bool hv = GUARD ? ((unsigned)hh < (unsigned)kH) : true;
        const int hc = GUARD ? min(max(hh, 0), kH - 1) : hh;
        const float* rowp = base + (size_t)(hc * kW) * 64 + 8 * j;
#pragma unroll
        for (int dx = -R; dx <= R; ++dx) {
            const int ww2 = w + dx;
            const int wc = GUARD ? min(max(ww2, 0), kW - 1) : ww2;
            float4 n0 = *(const float4*)(rowp + wc * 64);
            float4 n1 = *(const float4*)(rowp + wc * 64 + 4);
            if (GUARD) {
                const bool v = hv && ((unsigned)ww2 < (unsigned)kW);
                if (!v) {
                    n0 = make_float4(0.f, 0.f, 0.f, 0.f);
                    n1 = make_float4(0.f, 0.f, 0.f, 0.f);
                }
            }
            float d = n0.x * qs[0];
            d = fmaf(n0.y, qs[1], d);
            d = fmaf(n0.z, qs[2], d);
            d = fmaf(n0.w, qs[3], d);
            d = fmaf(n1.x, qs[4], d);
            d = fmaf(n1.y, qs[5], d);
            d = fmaf(n1.z, qs[6], d);
            d = fmaf(n1.w, qs[7], d);
            d += __shfl_xor(d, 1);
            d += __shfl_xor(d, 2);
            d += __shfl_xor(d, 4);
            const float pe = __builtin_amdgcn_exp2f(d);  // e^score (qs pre-scaled)
            l += pe;
            acc[0] = fmaf(pe, n0.x, acc[0]);
            acc[1] = fmaf(pe, n0.y, acc[1]);
            acc[2] = fmaf(pe, n0.z, acc[2]);
            acc[3] = fmaf(pe, n0.w, acc[3]);
            acc[4] = fmaf(pe, n1.x, acc[4]);
            acc[5] = fmaf(pe, n1.y, acc[5]);
            acc[6] = fmaf(pe, n1.z, acc[6]);
            acc[7] = fmaf(pe, n1.w, acc[7]);
        }
    }
}

// ---------------------------------------------------------------------------
// Kernel 2: fused 11x11 s->g attention, 5x5 g->s attention, 1x1 fusion conv.
// 8 lanes per pixel (8 channels/lane).
// ---------------------------------------------------------------------------
__global__ __launch_bounds__(256)
void attn_fuse(const float* __restrict__ gw, const float* __restrict__ sw,
               const float* __restrict__ w3, const float* __restrict__ b3,
               float* __restrict__ out, int nGroups)
{
    __shared__ float wt3[128 * 64];  // wt3[c][o] = w3[o][c], c in [0,128)
    for (int idx = threadIdx.x; idx < 8192; idx += 256) {
        const int o = idx >> 7, c = idx & 127;
        wt3[c * 64 + o] = w3[idx];
    }
    __syncthreads();

    const int tid = blockIdx.x * 256 + threadIdx.x;
    const int grp = tid >> 3;
    const int j   = tid & 7;

    float bb3[8];
    *(float4*)(bb3)     = *(const float4*)(b3 + 8 * j);
    *(float4*)(bb3 + 4) = *(const float4*)(b3 + 8 * j + 4);

    for (int p = grp; p < kNP; p += nGroups) {
        const int b   = p / kHW;
        const int rem = p - b * kHW;
        const int h   = rem / kW;
        const int w   = rem - h * kW;
        const float* gb = gw + (size_t)b * kHW * 64;
        const float* sb = sw + (size_t)b * kHW * 64;

        float gqs[8], svs[8];
        {
            const float4 g0 = *(const float4*)(gw + (size_t)p * 64 + 8 * j);
            const float4 g1 = *(const float4*)(gw + (size_t)p * 64 + 8 * j + 4);
            const float4 s0 = *(const float4*)(sw + (size_t)p * 64 + 8 * j);
            const float4 s1 = *(const float4*)(sw + (size_t)p * 64 + 8 * j + 4);
            gqs[0] = g0.x * kLog2e; gqs[1] = g0.y * kLog2e;
            gqs[2] = g0.z * kLog2e; gqs[3] = g0.w * kLog2e;
            gqs[4] = g1.x * kLog2e; gqs[5] = g1.y * kLog2e;
            gqs[6] = g1.z * kLog2e; gqs[7] = g1.w * kLog2e;
            svs[0] = s0.x * kLog2e; svs[1] = s0.y * kLog2e;
            svs[2] = s0.z * kLog2e; svs[3] = s0.w * kLog2e;
            svs[4] = s1.x * kLog2e; svs[5] = s1.y * kLog2e;
            svs[6] = s1.z * kLog2e; svs[7] = s1.w * kLog2e;
        }

        // ---- phase 1: source -> guide (11x11 over s, query = g pixel)
        float fs2g[8];
        {
            float acc[8] = {0.f, 0.f, 0.f, 0.f, 0.f, 0.f, 0.f, 0.f};
            float l = 0.f;
            if (h >= 5 && h < kH - 5 && w >= 5 && w < kW - 5)
                attn_phase<5, false>(sb, gqs, h, w, j, acc, l);
            else
                attn_phase<5, true>(sb, gqs, h, w, j, acc, l);
            const float inv = 1.0f / l;
#pragma unroll
            for (int k = 0; k < 8; ++k) fs2g[k] = acc[k] * inv;
        }

        // ---- phase 2: guide -> source (5x5 over g, query = s pixel)
        float fg2s[8];
        {
            float acc[8] = {0.f, 0.f, 0.f, 0.f, 0.f, 0.f, 0.f, 0.f};
            float l = 0.f;
            if (h >= 2 && h < kH - 2 && w >= 2 && w < kW - 2)
                attn_phase<2, false>(gb, svs, h, w, j, acc, l);
            else
                attn_phase<2, true>(gb, svs, h, w, j, acc, l);
            const float inv = 1.0f / l;
#pragma unroll
            for (int k = 0; k < 8; ++k) fg2s[k] = acc[k] * inv;
        }

        // ---- fusion: out[o] = sum_{c<64} w3[o][c]*fs2g[c]
        //                     + sum_{c<64} w3[o][64+c]*fg2s[c] + b3[o]
        float fo[8];
#pragma unroll
        for (int k = 0; k < 8; ++k) fo[k] = bb3[k];

        for (int c0 = 0; c0 < 64; c0 += 8) {
            const int sl = c0 >> 3;
#pragma unroll
            for (int k = 0; k < 8; ++k) {
                const float xc = __shfl(fs2g[k], sl, 8);
                const float* wr = &wt3[(c0 + k) * 64 + 8 * j];
                const float4 w0 = *(const float4*)(wr);
                const float4 w1v = *(const float4*)(wr + 4);
                fo[0] = fmaf(w0.x, xc, fo[0]);  fo[1] = fmaf(w0.y, xc, fo[1]);
                fo[2] = fmaf(w0.z, xc, fo[2]);  fo[3] = fmaf(w0.w, xc, fo[3]);
                fo[4] = fmaf(w1v.x, xc, fo[4]); fo[5] = fmaf(w1v.y, xc, fo[5]);
                fo[6] = fmaf(w1v.z, xc, fo[6]); fo[7] = fmaf(w1v.w, xc, fo[7]);
            }
        }
        for (int c0 = 0; c0 < 64; c0 += 8) {
            const int sl = c0 >> 3;
#pragma unroll
            for (int k = 0; k < 8; ++k) {
                const float xc = __shfl(fg2s[k], sl, 8);
                const float* wr = &wt3[(64 + c0 + k) * 64 + 8 * j];
                const float4 w0 = *(const float4*)(wr);
                const float4 w1v = *(const float4*)(wr + 4);
                fo[0] = fmaf(w0.x, xc, fo[0]);  fo[1] = fmaf(w0.y, xc, fo[1]);
                fo[2] = fmaf(w0.z, xc, fo[2]);  fo[3] = fmaf(w0.w, xc, fo[3]);
                fo[4] = fmaf(w1v.x, xc, fo[4]); fo[5] = fmaf(w1v.y, xc, fo[5]);
                fo[6] = fmaf(w1v.z, xc, fo[6]); fo[7] = fmaf(w1v.w, xc, fo[7]);
            }
        }

        // NCHW store: 8 strided scalar stores per lane
#pragma unroll
        for (int k = 0; k < 8; ++k) {
            out[((size_t)(b * kC + 8 * j + k) * kH + h) * kW + w] = fo[k];
        }
    }
}

extern "C" void kernel_launch(void* const* d_in, const int* in_sizes, int n_in,
                              void* d_out, int out_size, void* d_ws, size_t ws_size,
                              hipStream_t stream)
{
    const float* fg = (const float*)d_in[0];
    const float* fs = (const float*)d_in[1];
    const float* w1 = (const float*)d_in[2];
    const float* b1 = (const float*)d_in[3];
    const float* w2 = (const float*)d_in[4];
    const float* b2 = (const float*)d_in[5];
    const float* w3 = (const float*)d_in[6];
    const float* b3 = (const float*)d_in[7];
    float* outp = (float*)d_out;

    float* gws = (float*)d_ws;                 // (B,H,W,64) fp32, 6.4 MB
    float* sws = gws + (size_t)kNP * 64;       // (B,H,W,64) fp32, 6.4 MB

    // 784 blocks x 256 thr = 25088 8-lane groups -> exactly 1 pixel per group
    const int blocks = 784;
    const int nGroups = blocks * (256 / 8);
    conv_gs<<<blocks, 256, 0, stream>>>(fg, fs, w1, b1, w2, b2, gws, sws, nGroups);
    attn_fuse<<<blocks, 256, 0, stream>>>(gws, sws, w3, b3, outp, nGroups);
}

// Round 5
// 236.897 us; speedup vs baseline: 1.2574x; 1.2574x over previous
//
#include <hip/hip_runtime.h>
#include <hip/hip_bf16.h>

// Problem constants (fixed by setup_inputs)
constexpr int kH  = 112;
constexpr int kW  = 112;
constexpr int kC  = 64;
constexpr int kB  = 2;
constexpr int kHW = kH * kW;          // 12544
constexpr int kNP = kB * kHW;         // 25088 pixels

constexpr float kLog2e = 1.4426950408889634f;

// Tiling: 784 blocks = 2 batches x 28 bands(4 rows) x 14 tiles(8 wide).
// XCD swizzle (bijective, 784 = 8*98): physical bid -> logical tile d so each
// XCD owns 98 consecutive tiles = 28 contiguous pixel rows of one batch.
// conv_gs uses the SAME banding so the g/s workspace is produced in the L2 of
// the XCD that later consumes it in attn_fuse.
__device__ __forceinline__ int xcd_tile(int bid) {
    return (bid & 7) * 98 + (bid >> 3);
}

// ---------------------------------------------------------------------------
// Kernel 1: g = w1 @ f_guide + b1 ; s = w2 @ f_source + b2  (per-pixel 1x1)
// 8 lanes per pixel, 8 channels per lane. Output pixel-major (B,H,W,64) fp32.
// ---------------------------------------------------------------------------
__global__ __launch_bounds__(256, 4)
void conv_gs(const float* __restrict__ fg, const float* __restrict__ fs,
             const float* __restrict__ w1, const float* __restrict__ b1,
             const float* __restrict__ w2, const float* __restrict__ b2,
             float* __restrict__ gw, float* __restrict__ sw)
{
    __shared__ float wt1[64 * 64];   // wt1[c][o] = w1[o][c]
    __shared__ float wt2[64 * 64];
    // Conflict-free staging: consecutive lanes write consecutive o
    // (bank = o%32 -> 2-way across 64 lanes = free). Global read side is
    // strided but tiny (16KB x2, L1/L2-absorbed).
    for (int idx = threadIdx.x; idx < 4096; idx += 256) {
        const int c = idx >> 6, o = idx & 63;
        wt1[c * 64 + o] = w1[o * 64 + c];
        wt2[c * 64 + o] = w2[o * 64 + c];
    }
    __syncthreads();

    const int d = xcd_tile(blockIdx.x);
    const int p = d * 32 + (threadIdx.x >> 3);   // pixel id (same banding as attn)
    const int j = threadIdx.x & 7;               // lane owns channels 8j..8j+7

    const int b   = p / kHW;
    const int rem = p - b * kHW;
    const int h   = rem / kW;
    const int w   = rem - h * kW;

    float xg[8], xs[8];
#pragma unroll
    for (int cc = 0; cc < 8; ++cc) {
        const int a = ((b * kC + 8 * j + cc) * kH + h) * kW + w;
        xg[cc] = fg[a];
        xs[cc] = fs[a];
    }

    float ag[8], as_[8];
    {
        float bb1[8], bb2[8];
        *(float4*)(bb1)     = *(const float4*)(b1 + 8 * j);
        *(float4*)(bb1 + 4) = *(const float4*)(b1 + 8 * j + 4);
        *(float4*)(bb2)     = *(const float4*)(b2 + 8 * j);
        *(float4*)(bb2 + 4) = *(const float4*)(b2 + 8 * j + 4);
#pragma unroll
        for (int k = 0; k < 8; ++k) { ag[k] = bb1[k]; as_[k] = bb2[k]; }
    }

    for (int c0 = 0; c0 < 64; c0 += 8) {
        const int sl = c0 >> 3;
#pragma unroll
        for (int k = 0; k < 8; ++k) {
            const float xgc = __shfl(xg[k], sl, 8);
            const float xsc = __shfl(xs[k], sl, 8);
            const float* wr1 = &wt1[(c0 + k) * 64 + 8 * j];
            const float* wr2 = &wt2[(c0 + k) * 64 + 8 * j];
            const float4 a0 = *(const float4*)(wr1);
            const float4 a1 = *(const float4*)(wr1 + 4);
            const float4 c0v = *(const float4*)(wr2);
            const float4 c1v = *(const float4*)(wr2 + 4);
            ag[0] = fmaf(a0.x, xgc, ag[0]);  ag[1] = fmaf(a0.y, xgc, ag[1]);
            ag[2] = fmaf(a0.z, xgc, ag[2]);  ag[3] = fmaf(a0.w, xgc, ag[3]);
            ag[4] = fmaf(a1.x, xgc, ag[4]);  ag[5] = fmaf(a1.y, xgc, ag[5]);
            ag[6] = fmaf(a1.z, xgc, ag[6]);  ag[7] = fmaf(a1.w, xgc, ag[7]);
            as_[0] = fmaf(c0v.x, xsc, as_[0]); as_[1] = fmaf(c0v.y, xsc, as_[1]);
            as_[2] = fmaf(c0v.z, xsc, as_[2]); as_[3] = fmaf(c0v.w, xsc, as_[3]);
            as_[4] = fmaf(c1v.x, xsc, as_[4]); as_[5] = fmaf(c1v.y, xsc, as_[5]);
            as_[6] = fmaf(c1v.z, xsc, as_[6]); as_[7] = fmaf(c1v.w, xsc, as_[7]);
        }
    }
    float* gp = gw + (size_t)p * 64 + 8 * j;
    float* sp = sw + (size_t)p * 64 + 8 * j;
    *(float4*)(gp)     = make_float4(ag[0], ag[1], ag[2], ag[3]);
    *(float4*)(gp + 4) = make_float4(ag[4], ag[5], ag[6], ag[7]);
    *(float4*)(sp)     = make_float4(as_[0], as_[1], as_[2], as_[3]);
    *(float4*)(sp + 4) = make_float4(as_[4], as_[5], as_[6], as_[7]);
}

// ---------------------------------------------------------------------------
// Attention phase helper: R = radius (5 -> 11x11, 2 -> 5x5).
// qs = query channels (this lane's 8) pre-scaled by log2(e).
// No-max softmax: scores are bounded (|score| < ~50) so exp2 cannot overflow
// fp32. OOB neighbors are zero vectors -> score 0 -> weight 1 in the
// denominator, exactly matching the reference's zero-padded unfold.
// ---------------------------------------------------------------------------
template <int R, bool GUARD>
__device__ __forceinline__ void attn_phase(const float* __restrict__ base,
                                           const float qs[8], int h, int w, int j,
                                           float acc[8], float& l)
{
    for (int dy = -R; dy <= R; ++dy) {
        const int hh = h + dy;
        const bool hv = GUARD ? ((unsigned)hh < (unsigned)kH) : true;
        const int hc = GUARD ? min(max(hh, 0), kH - 1) : hh;
        const float* rowp = base + (size_t)(hc * kW) * 64 + 8 * j;
#pragma unroll
        for (int dx = -R; dx <= R; ++dx) {
            const int ww2 = w + dx;
            const int wc = GUARD ? min(max(ww2, 0), kW - 1) : ww2;
            float4 n0 = *(const float4*)(rowp + wc * 64);
            float4 n1 = *(const float4*)(rowp + wc * 64 + 4);
            if (GUARD) {
                const bool v = hv && ((unsigned)ww2 < (unsigned)kW);
                if (!v) {
                    n0 = make_float4(0.f, 0.f, 0.f, 0.f);
                    n1 = make_float4(0.f, 0.f, 0.f, 0.f);
                }
            }
            float d = n0.x * qs[0];
            d = fmaf(n0.y, qs[1], d);
            d = fmaf(n0.z, qs[2], d);
            d = fmaf(n0.w, qs[3], d);
            d = fmaf(n1.x, qs[4], d);
            d = fmaf(n1.y, qs[5], d);
            d = fmaf(n1.z, qs[6], d);
            d = fmaf(n1.w, qs[7], d);
            d += __shfl_xor(d, 1);
            d += __shfl_xor(d, 2);
            d += __shfl_xor(d, 4);
            const float pe = __builtin_amdgcn_exp2f(d);  // e^score (qs pre-scaled)
            l += pe;
            acc[0] = fmaf(pe, n0.x, acc[0]);
            acc[1] = fmaf(pe, n0.y, acc[1]);
            acc[2] = fmaf(pe, n0.z, acc[2]);
            acc[3] = fmaf(pe, n0.w, acc[3]);
            acc[4] = fmaf(pe, n1.x, acc[4]);
            acc[5] = fmaf(pe, n1.y, acc[5]);
            acc[6] = fmaf(pe, n1.z, acc[6]);
            acc[7] = fmaf(pe, n1.w, acc[7]);
        }
    }
}

// ---------------------------------------------------------------------------
// Kernel 2: fused 11x11 s->g attention, 5x5 g->s attention, 1x1 fusion conv.
// 8 lanes per pixel (8 channels/lane); block = 8x4 pixel tile, XCD-banded.
// ---------------------------------------------------------------------------
__global__ __launch_bounds__(256, 4)
void attn_fuse(const float* __restrict__ gw, const float* __restrict__ sw,
               const float* __restrict__ w3, const float* __restrict__ b3,
               float* __restrict__ out)
{
    __shared__ float wt3[128 * 64];  // wt3[c][o] = w3[o][c], c in [0,128)
    // Conflict-free staging (lanes vary o; global side L1/L2-absorbed).
    for (int idx = threadIdx.x; idx < 8192; idx += 256) {
        const int c = idx >> 6, o = idx & 63;
        wt3[c * 64 + o] = w3[o * 128 + c];
    }
    __syncthreads();

    const int d    = xcd_tile(blockIdx.x);
    const int b    = d / 392;
    const int r    = d - b * 392;
    const int band = r / 14;          // 28 bands of 4 pixel rows
    const int tw   = r - band * 14;   // 14 tiles of 8 pixels wide
    const int g    = threadIdx.x >> 3;
    const int j    = threadIdx.x & 7;
    const int h    = band * 4 + (g >> 3);
    const int w    = tw * 8 + (g & 7);
    const int p    = (b * kH + h) * kW + w;

    const float* gb = gw + (size_t)b * kHW * 64;
    const float* sb = sw + (size_t)b * kHW * 64;

    // ---- phase 1: source -> guide (11x11 over s, query = g pixel)
    float fs2g[8];
    {
        float gqs[8];
        const float4 g0 = *(const float4*)(gw + (size_t)p * 64 + 8 * j);
        const float4 g1 = *(const float4*)(gw + (size_t)p * 64 + 8 * j + 4);
        gqs[0] = g0.x * kLog2e; gqs[1] = g0.y * kLog2e;
        gqs[2] = g0.z * kLog2e; gqs[3] = g0.w * kLog2e;
        gqs[4] = g1.x * kLog2e; gqs[5] = g1.y * kLog2e;
        gqs[6] = g1.z * kLog2e; gqs[7] = g1.w * kLog2e;

        float acc[8] = {0.f, 0.f, 0.f, 0.f, 0.f, 0.f, 0.f, 0.f};
        float l = 0.f;
        if (h >= 5 && h < kH - 5 && w >= 5 && w < kW - 5)
            attn_phase<5, false>(sb, gqs, h, w, j, acc, l);
        else
            attn_phase<5, true>(sb, gqs, h, w, j, acc, l);
        const float inv = 1.0f / l;
#pragma unroll
        for (int k = 0; k < 8; ++k) fs2g[k] = acc[k] * inv;
    }

    // ---- phase 2: guide -> source (5x5 over g, query = s pixel)
    float fg2s[8];
    {
        float svs[8];
        const float4 s0 = *(const float4*)(sw + (size_t)p * 64 + 8 * j);
        const float4 s1 = *(const float4*)(sw + (size_t)p * 64 + 8 * j + 4);
        svs[0] = s0.x * kLog2e; svs[1] = s0.y * kLog2e;
        svs[2] = s0.z * kLog2e; svs[3] = s0.w * kLog2e;
        svs[4] = s1.x * kLog2e; svs[5] = s1.y * kLog2e;
        svs[6] = s1.z * kLog2e; svs[7] = s1.w * kLog2e;

        float acc[8] = {0.f, 0.f, 0.f, 0.f, 0.f, 0.f, 0.f, 0.f};
        float l = 0.f;
        if (h >= 2 && h < kH - 2 && w >= 2 && w < kW - 2)
            attn_phase<2, false>(gb, svs, h, w, j, acc, l);
        else
            attn_phase<2, true>(gb, svs, h, w, j, acc, l);
        const float inv = 1.0f / l;
#pragma unroll
        for (int k = 0; k < 8; ++k) fg2s[k] = acc[k] * inv;
    }

    // ---- fusion: out[o] = sum_{c<64} w3[o][c]*fs2g[c]
    //                     + sum_{c<64} w3[o][64+c]*fg2s[c] + b3[o]
    float fo[8];
    {
        float bb3[8];
        *(float4*)(bb3)     = *(const float4*)(b3 + 8 * j);
        *(float4*)(bb3 + 4) = *(const float4*)(b3 + 8 * j + 4);
#pragma unroll
        for (int k = 0; k < 8; ++k) fo[k] = bb3[k];
    }

    for (int c0 = 0; c0 < 64; c0 += 8) {
        const int sl = c0 >> 3;
#pragma unroll
        for (int k = 0; k < 8; ++k) {
            const float xc = __shfl(fs2g[k], sl, 8);
            const float* wr = &wt3[(c0 + k) * 64 + 8 * j];
            const float4 w0 = *(const float4*)(wr);
            const float4 w1v = *(const float4*)(wr + 4);
            fo[0] = fmaf(w0.x, xc, fo[0]);  fo[1] = fmaf(w0.y, xc, fo[1]);
            fo[2] = fmaf(w0.z, xc, fo[2]);  fo[3] = fmaf(w0.w, xc, fo[3]);
            fo[4] = fmaf(w1v.x, xc, fo[4]); fo[5] = fmaf(w1v.y, xc, fo[5]);
            fo[6] = fmaf(w1v.z, xc, fo[6]); fo[7] = fmaf(w1v.w, xc, fo[7]);
        }
    }
    for (int c0 = 0; c0 < 64; c0 += 8) {
        const int sl = c0 >> 3;
#pragma unroll
        for (int k = 0; k < 8; ++k) {
            const float xc = __shfl(fg2s[k], sl, 8);
            const float* wr = &wt3[(64 + c0 + k) * 64 + 8 * j];
            const float4 w0 = *(const float4*)(wr);
            const float4 w1v = *(const float4*)(wr + 4);
            fo[0] = fmaf(w0.x, xc, fo[0]);  fo[1] = fmaf(w0.y, xc, fo[1]);
            fo[2] = fmaf(w0.z, xc, fo[2]);  fo[3] = fmaf(w0.w, xc, fo[3]);
            fo[4] = fmaf(w1v.x, xc, fo[4]); fo[5] = fmaf(w1v.y, xc, fo[5]);
            fo[6] = fmaf(w1v.z, xc, fo[6]); fo[7] = fmaf(w1v.w, xc, fo[7]);
        }
    }

    // NCHW store: 8 strided scalar stores per lane
#pragma unroll
    for (int k = 0; k < 8; ++k) {
        out[((size_t)(b * kC + 8 * j + k) * kH + h) * kW + w] = fo[k];
    }
}

extern "C" void kernel_launch(void* const* d_in, const int* in_sizes, int n_in,
                              void* d_out, int out_size, void* d_ws, size_t ws_size,
                              hipStream_t stream)
{
    const float* fg = (const float*)d_in[0];
    const float* fs = (const float*)d_in[1];
    const float* w1 = (const float*)d_in[2];
    const float* b1 = (const float*)d_in[3];
    const float* w2 = (const float*)d_in[4];
    const float* b2 = (const float*)d_in[5];
    const float* w3 = (const float*)d_in[6];
    const float* b3 = (const float*)d_in[7];
    float* outp = (float*)d_out;

    float* gws = (float*)d_ws;                 // (B,H,W,64) fp32, 6.4 MB
    float* sws = gws + (size_t)kNP * 64;       // (B,H,W,64) fp32, 6.4 MB

    // 784 blocks x 256 thr; one pixel per 8-lane group, XCD-banded tiles.
    conv_gs<<<784, 256, 0, stream>>>(fg, fs, w1, b1, w2, b2, gws, sws);
    attn_fuse<<<784, 256, 0, stream>>>(gws, sws, w3, b3, outp);
}

// Round 6
// 182.580 us; speedup vs baseline: 1.6314x; 1.2975x over previous
//
#include <hip/hip_runtime.h>
#include <hip/hip_bf16.h>

// Problem constants (fixed by setup_inputs)
constexpr int kH  = 112;
constexpr int kW  = 112;
constexpr int kC  = 64;
constexpr int kB  = 2;
constexpr int kHW = kH * kW;          // 12544
constexpr int kNP = kB * kHW;         // 25088 pixels

constexpr float kLog2e = 1.4426950408889634f;

// XCD swizzles (bijective). Both kernels band pixels identically: XCD k owns
// pixels [k*3136, (k+1)*3136) == 28 contiguous rows of one batch, so the g/s
// workspace is produced in the L2 of the XCD that consumes it.
__device__ __forceinline__ int xcd1568(int bid) { return (bid & 7) * 196 + (bid >> 3); }
__device__ __forceinline__ int xcd3136(int bid) { return (bid & 7) * 392 + (bid >> 3); }

// ---------------------------------------------------------------------------
// Kernel 1: g = w1 @ f_guide + b1 ; s = w2 @ f_source + b2  (per-pixel 1x1)
// 16 lanes per pixel: team 0 (lanes 0-7) computes the g-conv, team 1 the
// s-conv; j = lane&7 owns 8 output channels. Output pixel-major (p,64) fp32.
// Blocks 0..31 additionally transpose w3 -> w3t[c][o] for the fusion stage.
// ---------------------------------------------------------------------------
__global__ __launch_bounds__(256, 6)
void conv_gs(const float* __restrict__ fg, const float* __restrict__ fs,
             const float* __restrict__ w1, const float* __restrict__ b1,
             const float* __restrict__ w2, const float* __restrict__ b2,
             const float* __restrict__ w3, float* __restrict__ gw,
             float* __restrict__ sw, float* __restrict__ w3t)
{
    __shared__ float wt[2][64 * 64];   // wt[t][c*64+o] = w_t[o][c]
    // Conflict-free staging: consecutive lanes write consecutive o.
    for (int idx = threadIdx.x; idx < 8192; idx += 256) {
        const int t = idx >> 12, rem = idx & 4095;
        const int c = rem >> 6, o = rem & 63;
        wt[t][c * 64 + o] = (t ? w2 : w1)[o * 64 + c];
    }
    // w3 transpose into workspace (once, by 32 physical blocks).
    if (blockIdx.x < 32) {
        const int idx = blockIdx.x * 256 + threadIdx.x;   // [0,8192)
        const int c = idx >> 6, o = idx & 63;
        w3t[idx] = w3[o * 128 + c];
    }
    __syncthreads();

    const int d = xcd1568(blockIdx.x);
    const int grp = threadIdx.x >> 4;       // 16 pixels/block
    const int i   = threadIdx.x & 15;
    const int t   = i >> 3;                 // 0: guide-conv, 1: source-conv
    const int j   = i & 7;                  // owns output channels 8j..8j+7
    const int p   = d * 16 + grp;

    const int b   = p / kHW;
    const int rem = p - b * kHW;
    const int h   = rem / kW;
    const int w   = rem - h * kW;

    const float* src  = t ? fs : fg;
    const float* bias = t ? b2 : b1;
    const float* wts  = wt[t];

    float x[8];
#pragma unroll
    for (int cc = 0; cc < 8; ++cc)
        x[cc] = src[((size_t)(b * kC + 8 * j + cc) * kH + h) * kW + w];

    float a[8];
    {
        const float4 bb0 = *(const float4*)(bias + 8 * j);
        const float4 bb1v = *(const float4*)(bias + 8 * j + 4);
        a[0] = bb0.x; a[1] = bb0.y; a[2] = bb0.z; a[3] = bb0.w;
        a[4] = bb1v.x; a[5] = bb1v.y; a[6] = bb1v.z; a[7] = bb1v.w;
    }

    for (int c0 = 0; c0 < 64; c0 += 8) {
        const int sl = c0 >> 3;
#pragma unroll
        for (int k = 0; k < 8; ++k) {
            const float xc = __shfl(x[k], sl, 8);     // broadcast within team
            const float* wr = &wts[(c0 + k) * 64 + 8 * j];
            const float4 w0 = *(const float4*)(wr);
            const float4 w1v = *(const float4*)(wr + 4);
            a[0] = fmaf(w0.x, xc, a[0]);  a[1] = fmaf(w0.y, xc, a[1]);
            a[2] = fmaf(w0.z, xc, a[2]);  a[3] = fmaf(w0.w, xc, a[3]);
            a[4] = fmaf(w1v.x, xc, a[4]); a[5] = fmaf(w1v.y, xc, a[5]);
            a[6] = fmaf(w1v.z, xc, a[6]); a[7] = fmaf(w1v.w, xc, a[7]);
        }
    }
    float* dst = (t ? sw : gw) + (size_t)p * 64 + 8 * j;
    *(float4*)(dst)     = make_float4(a[0], a[1], a[2], a[3]);
    *(float4*)(dst + 4) = make_float4(a[4], a[5], a[6], a[7]);
}

// ---------------------------------------------------------------------------
// Attention phase: NN = full neighbor count (121 or 25), KD = kernel width
// (11 or 5), RAD = radius. Team t of 4 handles neighbors n = t, t+4, ...
// (no-max softmax => partials merge by simple addition afterwards).
// qs pre-scaled by log2(e); scores bounded => exp2 can't overflow fp32.
// OOB neighbors are zero vectors -> score 0 -> weight 1 in the denominator,
// exactly matching the reference's zero-padded unfold.
// ---------------------------------------------------------------------------
template <int NN, int KD, int RAD, bool GUARD>
__device__ __forceinline__ void attn_phase(const float* __restrict__ base,
                                           const float qs[8], int pb, int h, int w,
                                           int t, int j, float acc[8], float& l)
{
    for (int n = t; n < NN; n += 4) {
        const int q = n / KD;            // magic-mul div (KD constexpr)
        const int r = n - q * KD;
        int off;
        bool valid = true;
        if (GUARD) {
            const int hh = h + q - RAD;
            const int ww = w + r - RAD;
            valid = ((unsigned)hh < (unsigned)kH) & ((unsigned)ww < (unsigned)kW);
            const int hc = min(max(hh, 0), kH - 1);
            const int wc = min(max(ww, 0), kW - 1);
            off = hc * kW + wc;
        } else {
            off = pb + q * kW + r - (RAD * kW + RAD);
        }
        const float* np = base + (size_t)off * 64 + 8 * j;
        float4 n0 = *(const float4*)(np);
        float4 n1 = *(const float4*)(np + 4);
        if (GUARD && !valid) {
            n0 = make_float4(0.f, 0.f, 0.f, 0.f);
            n1 = make_float4(0.f, 0.f, 0.f, 0.f);
        }
        float dd = n0.x * qs[0];
        dd = fmaf(n0.y, qs[1], dd);
        dd = fmaf(n0.z, qs[2], dd);
        dd = fmaf(n0.w, qs[3], dd);
        dd = fmaf(n1.x, qs[4], dd);
        dd = fmaf(n1.y, qs[5], dd);
        dd = fmaf(n1.z, qs[6], dd);
        dd = fmaf(n1.w, qs[7], dd);
        dd += __shfl_xor(dd, 1);         // reduce across the 8 j-lanes
        dd += __shfl_xor(dd, 2);
        dd += __shfl_xor(dd, 4);
        const float pe = __builtin_amdgcn_exp2f(dd);
        l += pe;
        acc[0] = fmaf(pe, n0.x, acc[0]);
        acc[1] = fmaf(pe, n0.y, acc[1]);
        acc[2] = fmaf(pe, n0.z, acc[2]);
        acc[3] = fmaf(pe, n0.w, acc[3]);
        acc[4] = fmaf(pe, n1.x, acc[4]);
        acc[5] = fmaf(pe, n1.y, acc[5]);
        acc[6] = fmaf(pe, n1.z, acc[6]);
        acc[7] = fmaf(pe, n1.w, acc[7]);
    }
}

// Merge team partials: 2-level butterfly leaves all 32 lanes with totals.
__device__ __forceinline__ void merge4(float acc[8], float& l)
{
    l += __shfl_xor(l, 8);
    l += __shfl_xor(l, 16);
#pragma unroll
    for (int k = 0; k < 8; ++k) {
        acc[k] += __shfl_xor(acc[k], 8);
        acc[k] += __shfl_xor(acc[k], 16);
    }
}

// ---------------------------------------------------------------------------
// Kernel 2: fused 11x11 s->g attention, 5x5 g->s attention, 1x1 fusion conv.
// 32 lanes per pixel: 4 teams of 8 split the neighbor loops; j = lane&7 owns
// 8 channels. No LDS. Fusion reads pre-transposed w3t (L1-hot, shared).
// ---------------------------------------------------------------------------
__global__ __launch_bounds__(256, 6)
void attn_fuse(const float* __restrict__ gw, const float* __restrict__ sw,
               const float* __restrict__ w3t, const float* __restrict__ b3,
               float* __restrict__ out)
{
    const int d   = xcd3136(blockIdx.x);
    const int grp = threadIdx.x >> 5;        // 8 pixels/block
    const int i   = threadIdx.x & 31;
    const int t   = i >> 3;                  // team 0..3
    const int j   = i & 7;                   // owns channels 8j..8j+7
    const int p   = d * 8 + grp;

    const int b  = p / kHW;
    const int pb = p - b * kHW;
    const int h  = pb / kW;
    const int w  = pb - h * kW;

    const float* gb = gw + (size_t)b * kHW * 64;
    const float* sb = sw + (size_t)b * kHW * 64;

    // ---- phase 1: source -> guide (11x11 over s, query = g pixel)
    float fs2g[8];
    {
        float qs[8];
        const float4 g0 = *(const float4*)(gw + (size_t)p * 64 + 8 * j);
        const float4 g1 = *(const float4*)(gw + (size_t)p * 64 + 8 * j + 4);
        qs[0] = g0.x * kLog2e; qs[1] = g0.y * kLog2e;
        qs[2] = g0.z * kLog2e; qs[3] = g0.w * kLog2e;
        qs[4] = g1.x * kLog2e; qs[5] = g1.y * kLog2e;
        qs[6] = g1.z * kLog2e; qs[7] = g1.w * kLog2e;

        float acc[8] = {0.f, 0.f, 0.f, 0.f, 0.f, 0.f, 0.f, 0.f};
        float l = 0.f;
        if (h >= 5 && h < kH - 5 && w >= 5 && w < kW - 5)
            attn_phase<121, 11, 5, false>(sb, qs, pb, h, w, t, j, acc, l);
        else
            attn_phase<121, 11, 5, true>(sb, qs, pb, h, w, t, j, acc, l);
        merge4(acc, l);
        const float inv = 1.0f / l;
#pragma unroll
        for (int k = 0; k < 8; ++k) fs2g[k] = acc[k] * inv;
    }

    // ---- phase 2: guide -> source (5x5 over g, query = s pixel)
    float fg2s[8];
    {
        float qs[8];
        const float4 s0 = *(const float4*)(sw + (size_t)p * 64 + 8 * j);
        const float4 s1 = *(const float4*)(sw + (size_t)p * 64 + 8 * j + 4);
        qs[0] = s0.x * kLog2e; qs[1] = s0.y * kLog2e;
        qs[2] = s0.z * kLog2e; qs[3] = s0.w * kLog2e;
        qs[4] = s1.x * kLog2e; qs[5] = s1.y * kLog2e;
        qs[6] = s1.z * kLog2e; qs[7] = s1.w * kLog2e;

        float acc[8] = {0.f, 0.f, 0.f, 0.f, 0.f, 0.f, 0.f, 0.f};
        float l = 0.f;
        if (h >= 2 && h < kH - 2 && w >= 2 && w < kW - 2)
            attn_phase<25, 5, 2, false>(gb, qs, pb, h, w, t, j, acc, l);
        else
            attn_phase<25, 5, 2, true>(gb, qs, pb, h, w, t, j, acc, l);
        merge4(acc, l);
        const float inv = 1.0f / l;
#pragma unroll
        for (int k = 0; k < 8; ++k) fg2s[k] = acc[k] * inv;
    }

    // ---- fusion: out[o] = sum_{c<128} w3t[c][o] * x[c] + b3[o],
    // x = [fs2g; fg2s]. 4-way c-split: team t owns w3t rows t*32..t*32+31
    // (teams 0,1 consume fs2g, teams 2,3 consume fg2s). Each lane
    // accumulates 8 outputs (8j..8j+7); butterfly-merge afterwards.
    float xsrc[8];
#pragma unroll
    for (int k = 0; k < 8; ++k) xsrc[k] = (t < 2) ? fs2g[k] : fg2s[k];

    float fo[8] = {0.f, 0.f, 0.f, 0.f, 0.f, 0.f, 0.f, 0.f};
    for (int m0 = 0; m0 < 32; m0 += 8) {
        const int srcl = (((t & 1) << 5) + m0) >> 3;        // broadcast lane
        const float* wrow = w3t + (size_t)(t * 32 + m0) * 64 + 8 * j;
#pragma unroll
        for (int mm = 0; mm < 8; ++mm) {
            const float xc = __shfl(xsrc[mm], srcl, 8);
            const float4 w0 = *(const float4*)(wrow + mm * 64);
            const float4 w1v = *(const float4*)(wrow + mm * 64 + 4);
            fo[0] = fmaf(w0.x, xc, fo[0]);  fo[1] = fmaf(w0.y, xc, fo[1]);
            fo[2] = fmaf(w0.z, xc, fo[2]);  fo[3] = fmaf(w0.w, xc, fo[3]);
            fo[4] = fmaf(w1v.x, xc, fo[4]); fo[5] = fmaf(w1v.y, xc, fo[5]);
            fo[6] = fmaf(w1v.z, xc, fo[6]); fo[7] = fmaf(w1v.w, xc, fo[7]);
        }
    }
#pragma unroll
    for (int k = 0; k < 8; ++k) {
        fo[k] += __shfl_xor(fo[k], 8);
        fo[k] += __shfl_xor(fo[k], 16);
    }

    // Store: team t writes channels 8j+2t and 8j+2t+1 (static reg indices).
    const float e0 = (t & 2) ? fo[4] : fo[0];
    const float e1 = (t & 2) ? fo[5] : fo[1];
    const float e2 = (t & 2) ? fo[6] : fo[2];
    const float e3 = (t & 2) ? fo[7] : fo[3];
    const float o0 = (t & 1) ? e2 : e0;
    const float o1 = (t & 1) ? e3 : e1;
    const int c0 = 8 * j + 2 * t;
    const size_t a0 = ((size_t)(b * kC + c0) * kH + h) * kW + w;
    out[a0]       = o0 + b3[c0];
    out[a0 + kHW] = o1 + b3[c0 + 1];
}

extern "C" void kernel_launch(void* const* d_in, const int* in_sizes, int n_in,
                              void* d_out, int out_size, void* d_ws, size_t ws_size,
                              hipStream_t stream)
{
    const float* fg = (const float*)d_in[0];
    const float* fs = (const float*)d_in[1];
    const float* w1 = (const float*)d_in[2];
    const float* b1 = (const float*)d_in[3];
    const float* w2 = (const float*)d_in[4];
    const float* b2 = (const float*)d_in[5];
    const float* w3 = (const float*)d_in[6];
    const float* b3 = (const float*)d_in[7];
    float* outp = (float*)d_out;

    float* gws = (float*)d_ws;                 // (p,64) fp32, 6.4 MB
    float* sws = gws + (size_t)kNP * 64;       // (p,64) fp32, 6.4 MB
    float* w3t = sws + (size_t)kNP * 64;       // 128x64 fp32, 32 KB

    // conv: 1568 blocks (16 px each); attn: 3136 blocks (8 px each).
    conv_gs<<<1568, 256, 0, stream>>>(fg, fs, w1, b1, w2, b2, w3, gws, sws, w3t);
    attn_fuse<<<3136, 256, 0, stream>>>(gws, sws, w3t, b3, outp);
}

// Round 11
// 174.158 us; speedup vs baseline: 1.7103x; 1.0484x over previous
//
#include <hip/hip_runtime.h>
#include <hip/hip_bf16.h>

// Problem constants (fixed by setup_inputs)
constexpr int kH  = 112;
constexpr int kW  = 112;
constexpr int kC  = 64;
constexpr int kB  = 2;
constexpr int kHW = kH * kW;          // 12544
constexpr int kNP = kB * kHW;         // 25088 pixels

constexpr float kLog2e = 1.4426950408889634f;

// XCD swizzles (bijective). Both kernels band pixels identically: XCD k owns
// pixels [k*3136, (k+1)*3136) == 28 contiguous rows of one batch, so the g/s
// workspace is produced in the L2 of the XCD that consumes it.
__device__ __forceinline__ int xcd1568(int bid) { return (bid & 7) * 196 + (bid >> 3); }
__device__ __forceinline__ int xcd3136(int bid) { return (bid & 7) * 392 + (bid >> 3); }

// ---------------------------------------------------------------------------
// Kernel 0: transpose weights into workspace (coalesced reads, scattered
// writes -- stores are fire-and-forget). w1t/w2t[c*64+o], w3t[c*64+o].
// ---------------------------------------------------------------------------
__global__ __launch_bounds__(256)
void prep(const float* __restrict__ w1, const float* __restrict__ w2,
          const float* __restrict__ w3, float* __restrict__ w1t,
          float* __restrict__ w2t, float* __restrict__ w3t)
{
    const int idx = blockIdx.x * 256 + threadIdx.x;   // [0, 16384)
    if (idx < 4096) {
        const int o = idx >> 6, c = idx & 63;
        w1t[c * 64 + o] = w1[idx];
    } else if (idx < 8192) {
        const int r = idx - 4096;
        const int o = r >> 6, c = r & 63;
        w2t[c * 64 + o] = w2[r];
    } else {
        const int r = idx - 8192;                     // [0, 8192)
        const int o = r >> 7, c = r & 127;
        w3t[c * 64 + o] = w3[r];
    }
}

// ---------------------------------------------------------------------------
// Kernel 1: g = w1 @ f_guide + b1 ; s = w2 @ f_source + b2  (per-pixel 1x1)
// 16 lanes per pixel: team 0 computes the g-conv, team 1 the s-conv; j=lane&7
// owns 8 output channels. Inputs staged via LDS with coalesced loads
// (lanes sweep 16 consecutive pixels); weights staged from pre-transposed
// w1t/w2t with contiguous reads. Output pixel-major (p,64) fp32.
// ---------------------------------------------------------------------------
__global__ __launch_bounds__(256, 4)
void conv_gs(const float* __restrict__ fg, const float* __restrict__ fs,
             const float* __restrict__ w1t, const float* __restrict__ b1,
             const float* __restrict__ w2t, const float* __restrict__ b2,
             float* __restrict__ gw, float* __restrict__ sw)
{
    __shared__ float wt[2][4096];       // wt[t][c*64+o]
    __shared__ float xls[2][64 * 17];   // xls[t][c*17+px], padded stride

    for (int idx = threadIdx.x; idx < 8192; idx += 256) {
        const int t = idx >> 12, rem = idx & 4095;
        wt[t][rem] = (t ? w2t : w1t)[rem];            // contiguous reads
    }

    const int d   = xcd1568(blockIdx.x);
    const int p0  = d * 16;
    const int b   = p0 / kHW;          // blocks never straddle batches (16|12544)
    const int pb0 = p0 - b * kHW;

    // Stage 16 pixels x 64 ch x {fg,fs}: lanes sweep px (16 consecutive
    // floats) then c -> 4 x 64B segments per wave-instr, fully coalesced.
    for (int idx = threadIdx.x; idx < 2048; idx += 256) {
        const int t  = idx >> 10;
        const int c  = (idx >> 4) & 63;
        const int px = idx & 15;
        xls[t][c * 17 + px] = (t ? fs : fg)[(size_t)(b * kC + c) * kHW + pb0 + px];
    }
    __syncthreads();

    const int grp = threadIdx.x >> 4;  // pixel within tile
    const int i   = threadIdx.x & 15;
    const int t   = i >> 3;            // 0: guide-conv, 1: source-conv
    const int j   = i & 7;             // owns output channels 8j..8j+7
    const int p   = p0 + grp;

    float x[8];
#pragma unroll
    for (int cc = 0; cc < 8; ++cc)
        x[cc] = xls[t][(8 * j + cc) * 17 + grp];

    const float* bias = t ? b2 : b1;
    const float* wts  = wt[t];

    float a[8];
    {
        const float4 bb0  = *(const float4*)(bias + 8 * j);
        const float4 bb1v = *(const float4*)(bias + 8 * j + 4);
        a[0] = bb0.x;  a[1] = bb0.y;  a[2] = bb0.z;  a[3] = bb0.w;
        a[4] = bb1v.x; a[5] = bb1v.y; a[6] = bb1v.z; a[7] = bb1v.w;
    }

    for (int c0 = 0; c0 < 64; c0 += 8) {
        const int sl = c0 >> 3;
#pragma unroll
        for (int k = 0; k < 8; ++k) {
            const float xc = __shfl(x[k], sl, 8);     // broadcast within team
            const float* wr = &wts[(c0 + k) * 64 + 8 * j];
            const float4 w0 = *(const float4*)(wr);
            const float4 w1v = *(const float4*)(wr + 4);
            a[0] = fmaf(w0.x, xc, a[0]);  a[1] = fmaf(w0.y, xc, a[1]);
            a[2] = fmaf(w0.z, xc, a[2]);  a[3] = fmaf(w0.w, xc, a[3]);
            a[4] = fmaf(w1v.x, xc, a[4]); a[5] = fmaf(w1v.y, xc, a[5]);
            a[6] = fmaf(w1v.z, xc, a[6]); a[7] = fmaf(w1v.w, xc, a[7]);
        }
    }
    float* dst = (t ? sw : gw) + (size_t)p * 64 + 8 * j;
    *(float4*)(dst)     = make_float4(a[0], a[1], a[2], a[3]);
    *(float4*)(dst + 4) = make_float4(a[4], a[5], a[6], a[7]);
}

// ---------------------------------------------------------------------------
// Attention phase: NN = neighbor count (121/25), KD = kernel width (11/5),
// RAD = radius. Team t of 4 handles neighbors n = t, t+4, ... with a
// distance-1 register prefetch pipeline (load n+4 while computing n).
// No-max softmax: partials merge by addition afterwards; qs pre-scaled by
// log2(e); scores bounded => exp2 can't overflow fp32. OOB neighbors are
// zero vectors -> score 0 -> weight 1 in the denominator (matches the
// reference's zero-padded unfold).
// ---------------------------------------------------------------------------
template <int NN, int KD, int RAD, bool GUARD>
__device__ __forceinline__ void attn_phase(const float* __restrict__ base,
                                           const float qs[8], int pb, int h, int w,
                                           int t, int j, float acc[8], float& l)
{
    const float* np;
    bool v0 = true;
    {
        const int q = t / KD, r = t - q * KD;
        int off;
        if (GUARD) {
            const int hh = h + q - RAD, ww = w + r - RAD;
            v0 = ((unsigned)hh < (unsigned)kH) & ((unsigned)ww < (unsigned)kW);
            off = min(max(hh, 0), kH - 1) * kW + min(max(ww, 0), kW - 1);
        } else {
            off = pb + q * kW + r - (RAD * kW + RAD);
        }
        np = base + (size_t)off * 64 + 8 * j;
    }
    float4 n0 = *(const float4*)(np);
    float4 n1 = *(const float4*)(np + 4);

    for (int n = t; n < NN; n += 4) {
        // prefetch neighbor n+4
        float4 m0, m1;
        bool v1 = true;
        if (n + 4 < NN) {
            const int q = (n + 4) / KD, r = (n + 4) - q * KD;
            int off;
            if (GUARD) {
                const int hh = h + q - RAD, ww = w + r - RAD;
                v1 = ((unsigned)hh < (unsigned)kH) & ((unsigned)ww < (unsigned)kW);
                off = min(max(hh, 0), kH - 1) * kW + min(max(ww, 0), kW - 1);
            } else {
                off = pb + q * kW + r - (RAD * kW + RAD);
            }
            const float* np2 = base + (size_t)off * 64 + 8 * j;
            m0 = *(const float4*)(np2);
            m1 = *(const float4*)(np2 + 4);
        }

        float4 c0 = n0, c1 = n1;
        if (GUARD && !v0) {
            c0 = make_float4(0.f, 0.f, 0.f, 0.f);
            c1 = make_float4(0.f, 0.f, 0.f, 0.f);
        }
        float dd = c0.x * qs[0];
        dd = fmaf(c0.y, qs[1], dd);
        dd = fmaf(c0.z, qs[2], dd);
        dd = fmaf(c0.w, qs[3], dd);
        dd = fmaf(c1.x, qs[4], dd);
        dd = fmaf(c1.y, qs[5], dd);
        dd = fmaf(c1.z, qs[6], dd);
        dd = fmaf(c1.w, qs[7], dd);
        dd += __shfl_xor(dd, 1);         // reduce across the 8 j-lanes
        dd += __shfl_xor(dd, 2);
        dd += __shfl_xor(dd, 4);
        const float pe = __builtin_amdgcn_exp2f(dd);
        l += pe;
        acc[0] = fmaf(pe, c0.x, acc[0]);
        acc[1] = fmaf(pe, c0.y, acc[1]);
        acc[2] = fmaf(pe, c0.z, acc[2]);
        acc[3] = fmaf(pe, c0.w, acc[3]);
        acc[4] = fmaf(pe, c1.x, acc[4]);
        acc[5] = fmaf(pe, c1.y, acc[5]);
        acc[6] = fmaf(pe, c1.z, acc[6]);
        acc[7] = fmaf(pe, c1.w, acc[7]);

        n0 = m0; n1 = m1; v0 = v1;
    }
}

// Merge team partials: 2-level butterfly leaves all 32 lanes with totals.
__device__ __forceinline__ void merge4(float acc[8], float& l)
{
    l += __shfl_xor(l, 8);
    l += __shfl_xor(l, 16);
#pragma unroll
    for (int k = 0; k < 8; ++k) {
        acc[k] += __shfl_xor(acc[k], 8);
        acc[k] += __shfl_xor(acc[k], 16);
    }
}

// ---------------------------------------------------------------------------
// Kernel 2: fused 11x11 s->g attention, 5x5 g->s attention, 1x1 fusion conv.
// 32 lanes per pixel: 4 teams of 8 split the neighbor loops; j = lane&7 owns
// 8 channels. No LDS. Fusion reads pre-transposed w3t (L1-hot, shared).
// ---------------------------------------------------------------------------
__global__ __launch_bounds__(256, 8)
void attn_fuse(const float* __restrict__ gw, const float* __restrict__ sw,
               const float* __restrict__ w3t, const float* __restrict__ b3,
               float* __restrict__ out)
{
    const int d   = xcd3136(blockIdx.x);
    const int grp = threadIdx.x >> 5;        // 8 pixels/block
    const int i   = threadIdx.x & 31;
    const int t   = i >> 3;                  // team 0..3
    const int j   = i & 7;                   // owns channels 8j..8j+7
    const int p   = d * 8 + grp;

    const int b  = p / kHW;
    const int pb = p - b * kHW;
    const int h  = pb / kW;
    const int w  = pb - h * kW;

    const float* gb = gw + (size_t)b * kHW * 64;
    const float* sb = sw + (size_t)b * kHW * 64;

    // ---- phase 1: source -> guide (11x11 over s, query = g pixel)
    float fs2g[8];
    {
        float qs[8];
        const float4 g0 = *(const float4*)(gw + (size_t)p * 64 + 8 * j);
        const float4 g1 = *(const float4*)(gw + (size_t)p * 64 + 8 * j + 4);
        qs[0] = g0.x * kLog2e; qs[1] = g0.y * kLog2e;
        qs[2] = g0.z * kLog2e; qs[3] = g0.w * kLog2e;
        qs[4] = g1.x * kLog2e; qs[5] = g1.y * kLog2e;
        qs[6] = g1.z * kLog2e; qs[7] = g1.w * kLog2e;

        float acc[8] = {0.f, 0.f, 0.f, 0.f, 0.f, 0.f, 0.f, 0.f};
        float l = 0.f;
        if (h >= 5 && h < kH - 5 && w >= 5 && w < kW - 5)
            attn_phase<121, 11, 5, false>(sb, qs, pb, h, w, t, j, acc, l);
        else
            attn_phase<121, 11, 5, true>(sb, qs, pb, h, w, t, j, acc, l);
        merge4(acc, l);
        const float inv = 1.0f / l;
#pragma unroll
        for (int k = 0; k < 8; ++k) fs2g[k] = acc[k] * inv;
    }

    // ---- phase 2: guide -> source (5x5 over g, query = s pixel)
    float fg2s[8];
    {
        float qs[8];
        const float4 s0 = *(const float4*)(sw + (size_t)p * 64 + 8 * j);
        const float4 s1 = *(const float4*)(sw + (size_t)p * 64 + 8 * j + 4);
        qs[0] = s0.x * kLog2e; qs[1] = s0.y * kLog2e;
        qs[2] = s0.z * kLog2e; qs[3] = s0.w * kLog2e;
        qs[4] = s1.x * kLog2e; qs[5] = s1.y * kLog2e;
        qs[6] = s1.z * kLog2e; qs[7] = s1.w * kLog2e;

        float acc[8] = {0.f, 0.f, 0.f, 0.f, 0.f, 0.f, 0.f, 0.f};
        float l = 0.f;
        if (h >= 2 && h < kH - 2 && w >= 2 && w < kW - 2)
            attn_phase<25, 5, 2, false>(gb, qs, pb, h, w, t, j, acc, l);
        else
            attn_phase<25, 5, 2, true>(gb, qs, pb, h, w, t, j, acc, l);
        merge4(acc, l);
        const float inv = 1.0f / l;
#pragma unroll
        for (int k = 0; k < 8; ++k) fg2s[k] = acc[k] * inv;
    }

    // ---- fusion: out[o] = sum_{c<128} w3t[c][o] * x[c] + b3[o],
    // x = [fs2g; fg2s]. Team t owns w3t rows t*32..t*32+31 (teams 0,1
    // consume fs2g, teams 2,3 consume fg2s); butterfly-merge afterwards.
    float xsrc[8];
#pragma unroll
    for (int k = 0; k < 8; ++k) xsrc[k] = (t < 2) ? fs2g[k] : fg2s[k];

    float fo[8] = {0.f, 0.f, 0.f, 0.f, 0.f, 0.f, 0.f, 0.f};
    for (int m0 = 0; m0 < 32; m0 += 8) {
        const int srcl = (((t & 1) << 5) + m0) >> 3;        // broadcast lane
        const float* wrow = w3t + (size_t)(t * 32 + m0) * 64 + 8 * j;
#pragma unroll
        for (int mm = 0; mm < 8; ++mm) {
            const float xc = __shfl(xsrc[mm], srcl, 8);
            const float4 w0 = *(const float4*)(wrow + mm * 64);
            const float4 w1v = *(const float4*)(wrow + mm * 64 + 4);
            fo[0] = fmaf(w0.x, xc, fo[0]);  fo[1] = fmaf(w0.y, xc, fo[1]);
            fo[2] = fmaf(w0.z, xc, fo[2]);  fo[3] = fmaf(w0.w, xc, fo[3]);
            fo[4] = fmaf(w1v.x, xc, fo[4]); fo[5] = fmaf(w1v.y, xc, fo[5]);
            fo[6] = fmaf(w1v.z, xc, fo[6]); fo[7] = fmaf(w1v.w, xc, fo[7]);
        }
    }
#pragma unroll
    for (int k = 0; k < 8; ++k) {
        fo[k] += __shfl_xor(fo[k], 8);
        fo[k] += __shfl_xor(fo[k], 16);
    }

    // Store: team t writes channels 8j+2t and 8j+2t+1 (static reg indices).
    const float e0 = (t & 2) ? fo[4] : fo[0];
    const float e1 = (t & 2) ? fo[5] : fo[1];
    const float e2 = (t & 2) ? fo[6] : fo[2];
    const float e3 = (t & 2) ? fo[7] : fo[3];
    const float o0 = (t & 1) ? e2 : e0;
    const float o1 = (t & 1) ? e3 : e1;
    const int c0 = 8 * j + 2 * t;
    const size_t a0 = ((size_t)(b * kC + c0) * kH + h) * kW + w;
    out[a0]       = o0 + b3[c0];
    out[a0 + kHW] = o1 + b3[c0 + 1];
}

extern "C" void kernel_launch(void* const* d_in, const int* in_sizes, int n_in,
                              void* d_out, int out_size, void* d_ws, size_t ws_size,
                              hipStream_t stream)
{
    const float* fg = (const float*)d_in[0];
    const float* fs = (const float*)d_in[1];
    const float* w1 = (const float*)d_in[2];
    const float* b1 = (const float*)d_in[3];
    const float* w2 = (const float*)d_in[4];
    const float* b2 = (const float*)d_in[5];
    const float* w3 = (const float*)d_in[6];
    const float* b3 = (const float*)d_in[7];
    float* outp = (float*)d_out;

    float* gws = (float*)d_ws;                 // (p,64) fp32, 6.4 MB
    float* sws = gws + (size_t)kNP * 64;       // (p,64) fp32, 6.4 MB
    float* w3t = sws + (size_t)kNP * 64;       // 128x64 fp32, 32 KB
    float* w1t = w3t + 128 * 64;               // 64x64 fp32, 16 KB
    float* w2t = w1t + 64 * 64;                // 64x64 fp32, 16 KB

    prep<<<64, 256, 0, stream>>>(w1, w2, w3, w1t, w2t, w3t);
    conv_gs<<<1568, 256, 0, stream>>>(fg, fs, w1t, b1, w2t, b2, gws, sws);
    attn_fuse<<<3136, 256, 0, stream>>>(gws, sws, w3t, b3, outp);
}